// Round 5
// baseline (136.871 us; speedup 1.0000x reference)
//
#include <hip/hip_runtime.h>
#include <hip/hip_bf16.h>
#include <stdint.h>
#include <math.h>

// DynaLoRALinear bf16-MFMA, 8-phase + one-phase-ahead frag prefetch (T1-T5).
// out = x@Wb^T + sum_e gates[e]*(x@A_e^T)@B_e^T, fused as out = [x|w] @ [Wb^T;B2], K=1088.

#define M_TOK 16384

typedef unsigned short u16;
typedef short bf16x8 __attribute__((ext_vector_type(8)));
typedef float f32x4 __attribute__((ext_vector_type(4)));
typedef __attribute__((address_space(3))) uint32_t lds_u32_t;
typedef __attribute__((address_space(1))) const uint32_t glb_u32_t;

__device__ __forceinline__ u16 f2bf(float f) {
  uint32_t u = __builtin_bit_cast(uint32_t, f);
  return (u16)((u + 0x7fffu + ((u >> 16) & 1u)) >> 16);  // RNE
}
__device__ __forceinline__ float bf2f(u16 v) {
  return __builtin_bit_cast(float, (uint32_t)v << 16);
}

// ---------------- f32 -> bf16 convert, 4 elems/thread ----------------
__global__ __launch_bounds__(256) void cvt_k(const float* __restrict__ in,
                                             u16* __restrict__ out, int n4) {
  int i = blockIdx.x * 256 + threadIdx.x;
  if (i >= n4) return;
  float4 v = ((const float4*)in)[i];
  ushort4 o;
  o.x = f2bf(v.x); o.y = f2bf(v.y); o.z = f2bf(v.z); o.w = f2bf(v.w);
  ((ushort4*)out)[i] = o;
}

// ---------------- Wb [1024][1024] f32 -> Btb cols 0..1023 (stride 1088) ------
__global__ __launch_bounds__(256) void cvt_wb_k(const float* __restrict__ in,
                                                u16* __restrict__ out) {
  int i = blockIdx.x * 256 + threadIdx.x;
  int idx = i * 4;
  int row = idx >> 10, col = idx & 1023;
  float4 v = ((const float4*)in)[i];
  ushort4 o;
  o.x = f2bf(v.x); o.y = f2bf(v.y); o.z = f2bf(v.z); o.w = f2bf(v.w);
  *(ushort4*)(out + (size_t)row * 1088 + col) = o;
}

// ---------------- lora_B [8][1024][8] -> Btb cols 1024..1087 ----------------
__global__ __launch_bounds__(256) void b2_gather_k(const float* __restrict__ loraB,
                                                   u16* __restrict__ Btb) {
  int idx = blockIdx.x * 256 + threadIdx.x;  // 1024*64
  int n = idx >> 6, q = idx & 63;
  int e = q >> 3, r = q & 7;
  Btb[(size_t)n * 1088 + 1024 + q] = f2bf(loraB[((size_t)(e * 1024 + n)) * 8 + r]);
}

// ---------------- router: logits + softmax, one wave per token ----------------
__global__ __launch_bounds__(256) void gates_kernel(const u16* __restrict__ h,
                                                    const float* __restrict__ W2,
                                                    const float* __restrict__ b2,
                                                    const float* __restrict__ temp,
                                                    float* __restrict__ gates) {
  int wave = threadIdx.x >> 6, lane = threadIdx.x & 63;
  int m = blockIdx.x * 4 + wave;
  bf16x8 hv8 = *(const bf16x8*)(h + (size_t)m * 512 + lane * 8);
  float hv[8];
#pragma unroll
  for (int j = 0; j < 8; ++j) hv[j] = bf2f((u16)hv8[j]);
  float p[8] = {};
#pragma unroll
  for (int e = 0; e < 8; ++e) {
    const float* w2r = W2 + e * 512 + lane * 8;
#pragma unroll
    for (int j = 0; j < 8; ++j) p[e] += hv[j] * w2r[j];
  }
#pragma unroll
  for (int off = 32; off > 0; off >>= 1) {
#pragma unroll
    for (int e = 0; e < 8; ++e) p[e] += __shfl_down(p[e], off);
  }
  if (lane == 0) {
    float t = temp[0];
    float lg[8], mx = -1e30f;
#pragma unroll
    for (int e = 0; e < 8; ++e) { lg[e] = (p[e] + b2[e]) / t; mx = fmaxf(mx, lg[e]); }
    float s = 0.f;
#pragma unroll
    for (int e = 0; e < 8; ++e) { lg[e] = expf(lg[e] - mx); s += lg[e]; }
    float inv = 1.f / s;
#pragma unroll
    for (int e = 0; e < 8; ++e) gates[(size_t)m * 8 + e] = lg[e] * inv;
  }
}

// ---------------- m97-style GEMM kept for the small w-GEMM (MODE 1) ----------
template <int BM, int BN, int MODE>
__global__ __launch_bounds__(256) void gemm_mfma(const u16* __restrict__ A,
                                                 const u16* __restrict__ Bt,
                                                 const u16* __restrict__ A2,
                                                 void* __restrict__ Cv,
                                                 const float* __restrict__ aux,
                                                 int N, int K, int lda, int ldb) {
  constexpr int FM = BM / 32, FN = BN / 32;
  constexpr int AI = BM / 32, BI = BN / 32;
  __shared__ u16 lds[(BM + BN) * 64];
  u16* As = lds;
  u16* Bs = lds + BM * 64;

  const int tid = threadIdx.x;
  const int w = tid >> 6, lane = tid & 63;
  const int wr = w >> 1, wc = w & 1;
  const int m0 = blockIdx.y * BM, n0 = blockIdx.x * BN;

  const uint8_t* Ab = (const uint8_t*)A;
  const uint8_t* Bb = (const uint8_t*)Bt;
  const size_t lda_b = (size_t)lda * 2, ldb_b = (size_t)ldb * 2;

  f32x4 acc[FM][FN] = {};

  const int nk = K >> 6;
  for (int kt = 0; kt < nk; ++kt) {
#pragma unroll
    for (int i = 0; i < AI; ++i) {
      const int lbase = (w * AI + i) * 1024;
      const int o = lbase + lane * 16;
      const int r = o >> 7, cb = o & 127;
      const uint8_t* g = Ab + (size_t)(m0 + r) * lda_b + (size_t)kt * 128 + cb;
      __builtin_amdgcn_global_load_lds((glb_u32_t*)g,
                                       (lds_u32_t*)((uint8_t*)As + lbase), 16, 0, 0);
    }
#pragma unroll
    for (int i = 0; i < BI; ++i) {
      const int lbase = (w * BI + i) * 1024;
      const int o = lbase + lane * 16;
      const int r = o >> 7, cb = o & 127;
      const uint8_t* g = Bb + (size_t)(n0 + r) * ldb_b + (size_t)kt * 128 + cb;
      __builtin_amdgcn_global_load_lds((glb_u32_t*)g,
                                       (lds_u32_t*)((uint8_t*)Bs + lbase), 16, 0, 0);
    }
    __syncthreads();

    bf16x8 af[2][FM], bfv[2][FN];
#pragma unroll
    for (int ks = 0; ks < 2; ++ks) {
      const int col = ks * 32 + ((lane >> 4) << 3);
#pragma unroll
      for (int im = 0; im < FM; ++im) {
        const int row = wr * (BM / 2) + im * 16 + (lane & 15);
        af[ks][im] = *(const bf16x8*)(As + row * 64 + col);
      }
#pragma unroll
      for (int in_ = 0; in_ < FN; ++in_) {
        const int row = wc * (BN / 2) + in_ * 16 + (lane & 15);
        bfv[ks][in_] = *(const bf16x8*)(Bs + row * 64 + col);
      }
    }
#pragma unroll
    for (int ks = 0; ks < 2; ++ks)
#pragma unroll
      for (int im = 0; im < FM; ++im)
#pragma unroll
        for (int in_ = 0; in_ < FN; ++in_)
          acc[im][in_] = __builtin_amdgcn_mfma_f32_16x16x32_bf16(
              af[ks][im], bfv[ks][in_], acc[im][in_], 0, 0, 0);
    __syncthreads();
  }

#pragma unroll
  for (int im = 0; im < FM; ++im)
#pragma unroll
    for (int in_ = 0; in_ < FN; ++in_) {
      const int col = n0 + wc * (BN / 2) + in_ * 16 + (lane & 15);
#pragma unroll
      for (int j = 0; j < 4; ++j) {
        const int row = m0 + wr * (BM / 2) + im * 16 + ((lane >> 4) << 2) + j;
        float v = acc[im][in_][j];
        if constexpr (MODE == 1) {
          v *= aux[(size_t)row * 8 + (col >> 3)];
          ((u16*)Cv)[(size_t)row * N + col] = f2bf(v);
        } else {
          ((float*)Cv)[(size_t)row * N + col] = v;
        }
      }
    }
}

// ====== 8-phase GEMM, one-phase-ahead frag prefetch + counted vmcnt (T1-T5) ======
// C[m][n] = sum_k A[m][k]*Bt[n][k]. 512 thr = 8 waves (2M x 4N), per-wave BM/2 x BN/4.
// Phase p: [stage future half-tile][VMCNT @P4/P8][BAR][ds_reads for phase p+1]
//          [SP1; MFMA consuming frags read at p-1; SP0][BAR]
// -> LDS-read drain of p+1 overlaps MFMA of p; lgkm wait before MFMA ~free.
// MODE 0: bf16 relu(acc+aux[n]).  MODE 2: last K-tile's A from A2 (128B rows), f32 store.
#define MFMA_Q2(mh, nh, AF, BF)                                                \
  _Pragma("unroll") for (int im2 = 0; im2 < FMH; ++im2)                        \
  _Pragma("unroll") for (int in2 = 0; in2 < FNH; ++in2)                        \
  _Pragma("unroll") for (int ks = 0; ks < 2; ++ks)                             \
      acc[(mh) * FMH + im2][(nh) * FNH + in2] =                                \
          __builtin_amdgcn_mfma_f32_16x16x32_bf16(                             \
              AF[im2][ks], BF[in2][ks],                                        \
              acc[(mh) * FMH + im2][(nh) * FNH + in2], 0, 0, 0);

#define VMCNT(n) asm volatile("s_waitcnt vmcnt(%0)" ::"i"(n) : "memory")
#define BAR asm volatile("s_barrier" ::: "memory")
#define SP(x) __builtin_amdgcn_s_setprio(x)

template <int BM, int BN, int MODE>
__global__ __launch_bounds__(512, 2) void gemm8p(const u16* __restrict__ A,
                                                 const u16* __restrict__ Bt,
                                                 const u16* __restrict__ A2,
                                                 void* __restrict__ Cv,
                                                 const float* __restrict__ aux,
                                                 const int N, const int K,
                                                 const int lda, const int ldb) {
  constexpr int FM = BM / 32;                   // m-frags per wave (BM/2 rows)
  constexpr int FNW = BN / 64;                  // n-frags per wave (BN/4 cols)
  constexpr int FMH = FM / 2;
  constexpr int FNH = (FNW >= 2) ? FNW / 2 : 1;
  constexpr int NBH = BN / 128;                 // B half-tiles per K-tile (2 or 1)
  constexpr int VMC = 2 * NBH;                  // counted vmcnt
  constexpr int BUFB = (BM + BN) * 128;         // bytes per K-tile buffer

  __shared__ __align__(16) uint8_t lds[2 * BUFB];

  const int tid = threadIdx.x;
  const int lane = tid & 63, w = tid >> 6;
  const int wr = w >> 2, wcn = w & 3;
  const int l15 = lane & 15, lhi = lane >> 4;
  const int xorv = (lane & 7) << 4;
  const int c0 = (lhi * 16) ^ xorv;        // ks=0 col-byte (swizzled)
  const int c1 = (64 + lhi * 16) ^ xorv;   // ks=1

  // T1: bijective XCD swizzle; grid is exactly 256 blocks (32 per XCD).
  const int f = blockIdx.x;
  const int idx = (f & 7) * 32 + (f >> 3);
  const int gx = N / BN;
  const int m0 = (idx / gx) * BM;
  const int n0 = (idx % gx) * BN;

  const size_t lda_b = (size_t)lda * 2, ldb_b = (size_t)ldb * 2;
  const int nk = K >> 6;

  const int arow0 = (wr * (BM / 2) + l15) * 128;
  const int brow0 = (wcn * (BN / 4) + l15) * 128;

  f32x4 acc[FM][FNW] = {};
  bf16x8 A0f[FMH][2], A1f[FMH][2];
  bf16x8 B0a[FNH][2], B0b[FNH][2], B1f[FNH][2];

  // ---- stage one 16KB half-tile (2 global_load_lds per wave) ----
  auto stageA = [&](int h, int kt, int b) {
    const int ktc = kt < nk ? kt : nk - 1;
    const bool last = (MODE == 2) && (ktc == nk - 1);
    uint8_t* dst = lds + b * BUFB + h * (BM * 64) + w * 1024;
#pragma unroll
    for (int i = 0; i < 2; ++i) {
      const int off = i * 8192 + tid * 16;
      const int row = h * (BM / 2) + (off >> 7);
      const int ss = ((off >> 4) & 7) ^ (row & 7);  // inverse-swizzled source
      const uint8_t* g =
          last ? (const uint8_t*)A2 + (size_t)(m0 + row) * 128 + ss * 16
               : (const uint8_t*)A + (size_t)(m0 + row) * lda_b + ktc * 128 + ss * 16;
      __builtin_amdgcn_global_load_lds((glb_u32_t*)g, (lds_u32_t*)(dst + i * 8192),
                                       16, 0, 0);
    }
  };
  auto stageB = [&](int h, int kt, int b) {
    const int ktc = kt < nk ? kt : nk - 1;
    uint8_t* dst = lds + b * BUFB + BM * 128 + h * (BN * 64) + w * 1024;
#pragma unroll
    for (int i = 0; i < 2; ++i) {
      const int off = i * 8192 + tid * 16;
      const int row = h * (BN / 2) + (off >> 7);
      const int ss = ((off >> 4) & 7) ^ (row & 7);
      const uint8_t* g =
          (const uint8_t*)Bt + (size_t)(n0 + row) * ldb_b + ktc * 128 + ss * 16;
      __builtin_amdgcn_global_load_lds((glb_u32_t*)g, (lds_u32_t*)(dst + i * 8192),
                                       16, 0, 0);
    }
  };

  auto loadA = [&](int mh, const uint8_t* buf, bf16x8 (&dst)[FMH][2]) {
#pragma unroll
    for (int im2 = 0; im2 < FMH; ++im2) {
      const uint8_t* p = buf + arow0 + mh * (FMH * 2048) + im2 * 2048;
      dst[im2][0] = *(const bf16x8*)(p + c0);
      dst[im2][1] = *(const bf16x8*)(p + c1);
    }
  };
  auto loadB = [&](int nh, const uint8_t* buf, bf16x8 (&dst)[FNH][2]) {
#pragma unroll
    for (int in2 = 0; in2 < FNH; ++in2) {
      const uint8_t* p = buf + BM * 128 + brow0 + nh * (FNH * 2048) + in2 * 2048;
      dst[in2][0] = *(const bf16x8*)(p + c0);
      dst[in2][1] = *(const bf16x8*)(p + c1);
    }
  };

  const uint8_t* b0 = lds;
  const uint8_t* b1 = lds + BUFB;

  // ---- prologue: tile0 (A+B) -> buf0, tile1 B -> buf1; pre-read A0,B0(0) ----
  stageA(0, 0, 0); stageA(1, 0, 0);
  stageB(0, 0, 0); if constexpr (NBH == 2) stageB(1, 0, 0);
  stageB(0, 1, 1); if constexpr (NBH == 2) stageB(1, 1, 1);
  VMCNT(VMC); BAR;
  loadA(0, b0, A0f); loadB(0, b0, B0a);

  const int NIT = nk >> 1;
  for (int it = 0; it < NIT; ++it) {
    const int t = it * 2;
    // P1: MFMA Q(0,0|t); read B1(t)
    stageA(0, t + 1, 1);
    BAR;
    loadB(1, b0, B1f);
    SP(1); MFMA_Q2(0, 0, A0f, B0a); SP(0); BAR;
    // P2: Q(0,1|t); read A1(t)
    stageA(1, t + 1, 1);
    BAR;
    loadA(1, b0, A1f);
    SP(1); MFMA_Q2(0, 1, A0f, B1f); SP(0); BAR;
    // P3: Q(1,1|t); no reads (P4 reuses A1,B0a)
    stageB(0, t + 2, 0);
    BAR;
    SP(1); MFMA_Q2(1, 1, A1f, B1f); SP(0); BAR;
    // P4: Q(1,0|t); vmcnt completes tile t+1 -> read A0,B0(t+1)
    if constexpr (NBH == 2) stageB(1, t + 2, 0);
    VMCNT(VMC);
    BAR;
    loadA(0, b1, A0f); loadB(0, b1, B0b);
    SP(1); MFMA_Q2(1, 0, A1f, B0a); SP(0); BAR;
    // P5: Q(0,0|t+1); read B1(t+1)
    stageA(0, t + 2, 0);
    BAR;
    loadB(1, b1, B1f);
    SP(1); MFMA_Q2(0, 0, A0f, B0b); SP(0); BAR;
    // P6: Q(0,1|t+1); read A1(t+1)
    stageA(1, t + 2, 0);
    BAR;
    loadA(1, b1, A1f);
    SP(1); MFMA_Q2(0, 1, A0f, B1f); SP(0); BAR;
    // P7: Q(1,1|t+1); no reads
    stageB(0, t + 3, 1);
    BAR;
    SP(1); MFMA_Q2(1, 1, A1f, B1f); SP(0); BAR;
    // P8: Q(1,0|t+1); vmcnt completes tile t+2 -> read A0,B0(t+2)
    if constexpr (NBH == 2) stageB(1, t + 3, 1);
    VMCNT(VMC);
    BAR;
    loadA(0, b0, A0f); loadB(0, b0, B0a);
    SP(1); MFMA_Q2(1, 0, A1f, B0b); SP(0); BAR;
  }

  // ---- tail K-tile (odd nk): buf0 holds tile nk-1; A0f/B0a pre-read at last P8 ----
  if (nk & 1) {
    loadB(1, b0, B1f);
    SP(1); MFMA_Q2(0, 0, A0f, B0a); SP(0);
    loadA(1, b0, A1f);
    SP(1); MFMA_Q2(0, 1, A0f, B1f); SP(0);
    SP(1); MFMA_Q2(1, 1, A1f, B1f); MFMA_Q2(1, 0, A1f, B0a); SP(0);
  }

  // ---- epilogue: C/D map col=lane&15, row=(lane>>4)*4+j ----
#pragma unroll
  for (int im = 0; im < FM; ++im) {
#pragma unroll
    for (int in_ = 0; in_ < FNW; ++in_) {
      const int col = n0 + wcn * (BN / 4) + in_ * 16 + l15;
#pragma unroll
      for (int j = 0; j < 4; ++j) {
        const int row = m0 + wr * (BM / 2) + im * 16 + lhi * 4 + j;
        float v = acc[im][in_][j];
        if constexpr (MODE == 0) {
          v = fmaxf(v + aux[col], 0.f);
          ((u16*)Cv)[(size_t)row * N + col] = f2bf(v);
        } else {
          ((float*)Cv)[(size_t)row * N + col] = v;
        }
      }
    }
  }
}

extern "C" void kernel_launch(void* const* d_in, const int* in_sizes, int n_in,
                              void* d_out, int out_size, void* d_ws, size_t ws_size,
                              hipStream_t stream) {
  const float* x     = (const float*)d_in[0];  // [16384][1024]
  const float* Wb    = (const float*)d_in[1];  // [1024][1024]
  const float* rW1   = (const float*)d_in[2];  // [512][1024]
  const float* rb1   = (const float*)d_in[3];  // [512]
  const float* rW2   = (const float*)d_in[4];  // [8][512]
  const float* rb2   = (const float*)d_in[5];  // [8]
  const float* temp  = (const float*)d_in[6];  // [1]
  const float* loraA = (const float*)d_in[7];  // [64][1024]
  const float* loraB = (const float*)d_in[8];  // [8][1024][8]
  float* out = (float*)d_out;

  uint8_t* p = (uint8_t*)d_ws;
  u16* xb   = (u16*)p;                 p += (size_t)M_TOK * 1024 * 2;
  u16* hb   = (u16*)p;                 p += (size_t)M_TOK * 512 * 2;
  u16* wb   = (u16*)p;                 p += (size_t)M_TOK * 64 * 2;
  u16* Btb  = (u16*)p;                 p += (size_t)1024 * 1088 * 2;
  u16* W1b  = (u16*)p;                 p += (size_t)512 * 1024 * 2;
  u16* A2b  = (u16*)p;                 p += (size_t)64 * 1024 * 2;
  float* gates = (float*)p;

  // ---- prep: bf16 conversions ----
  cvt_k<<<(M_TOK * 1024 / 4) / 256, 256, 0, stream>>>(x, xb, M_TOK * 1024 / 4);
  cvt_wb_k<<<(1024 * 1024 / 4) / 256, 256, 0, stream>>>(Wb, Btb);
  b2_gather_k<<<(1024 * 64) / 256, 256, 0, stream>>>(loraB, Btb);
  cvt_k<<<(512 * 1024 / 4) / 256, 256, 0, stream>>>(rW1, W1b, 512 * 1024 / 4);
  cvt_k<<<(64 * 1024 / 4) / 256, 256, 0, stream>>>(loraA, A2b, 64 * 1024 / 4);

  // ---- h = relu(x @ W1^T + b1) -> bf16 [16384][512] (8-phase) ----
  gemm8p<256, 128, 0><<<256, 512, 0, stream>>>(xb, W1b, nullptr, hb, rb1,
                                               512, 1024, 1024, 1024);

  // ---- gates = softmax((h @ W2^T + b2)/T) ----
  gates_kernel<<<M_TOK / 4, 256, 0, stream>>>(hb, rW2, rb2, temp, gates);

  // ---- w = (x @ A^T) * gate -> bf16 [16384][64] (m97-style, 256 blocks) ----
  gemm_mfma<64, 64, 1><<<dim3(1, M_TOK / 64), 256, 0, stream>>>(
      xb, A2b, nullptr, wb, gates, 64, 1024, 1024, 1024);

  // ---- out = [x | w] @ [Wb^T ; B2] -> f32 [16384][1024], K=1088 (8-phase) ----
  gemm8p<256, 256, 2><<<256, 512, 0, stream>>>(xb, Btb, wb, out, nullptr,
                                               1024, 1088, 1024, 1088);
}

// Round 6
// 110.098 us; speedup vs baseline: 1.2432x; 1.2432x over previous
//
#include <hip/hip_runtime.h>
#include <hip/hip_bf16.h>
#include <stdint.h>
#include <math.h>

// DynaLoRALinear bf16-MFMA, round-4 proven 8-phase schedule + fused prep.
// out = x@Wb^T + sum_e gates[e]*(x@A_e^T)@B_e^T, fused as out = [x|w] @ [Wb^T;B2], K=1088.

#define M_TOK 16384

typedef unsigned short u16;
typedef short bf16x8 __attribute__((ext_vector_type(8)));
typedef float f32x4 __attribute__((ext_vector_type(4)));
typedef __attribute__((address_space(3))) uint32_t lds_u32_t;
typedef __attribute__((address_space(1))) const uint32_t glb_u32_t;

__device__ __forceinline__ u16 f2bf(float f) {
  uint32_t u = __builtin_bit_cast(uint32_t, f);
  return (u16)((u + 0x7fffu + ((u >> 16) & 1u)) >> 16);  // RNE
}
__device__ __forceinline__ float bf2f(u16 v) {
  return __builtin_bit_cast(float, (uint32_t)v << 16);
}

// ---------------- fused prep: all f32->bf16 conversions + gathers ----------------
// blocks [0,16384): x -> xb (4.19M float4 groups)
// blocks [16384,17408): Wb -> Btb cols 0..1023 (stride 1088)
// blocks [17408,17920): rW1 -> W1b
// blocks [17920,18176): lora_B gather -> Btb cols 1024..1087
// blocks [18176,18240): lora_A -> A2b
__global__ __launch_bounds__(256) void prep_k(const float* __restrict__ x,
                                              const float* __restrict__ Wb,
                                              const float* __restrict__ rW1,
                                              const float* __restrict__ loraA,
                                              const float* __restrict__ loraB,
                                              u16* __restrict__ xb,
                                              u16* __restrict__ Btb,
                                              u16* __restrict__ W1b,
                                              u16* __restrict__ A2b) {
  const int g = blockIdx.x;
  const int tid = threadIdx.x;
  if (g < 16384) {
    int i = g * 256 + tid;
    float4 v = ((const float4*)x)[i];
    ushort4 o;
    o.x = f2bf(v.x); o.y = f2bf(v.y); o.z = f2bf(v.z); o.w = f2bf(v.w);
    ((ushort4*)xb)[i] = o;
  } else if (g < 17408) {
    int i = (g - 16384) * 256 + tid;          // 262144 float4 groups
    int idx = i * 4;
    int row = idx >> 10, col = idx & 1023;
    float4 v = ((const float4*)Wb)[i];
    ushort4 o;
    o.x = f2bf(v.x); o.y = f2bf(v.y); o.z = f2bf(v.z); o.w = f2bf(v.w);
    *(ushort4*)(Btb + (size_t)row * 1088 + col) = o;
  } else if (g < 17920) {
    int i = (g - 17408) * 256 + tid;          // 131072 float4 groups
    float4 v = ((const float4*)rW1)[i];
    ushort4 o;
    o.x = f2bf(v.x); o.y = f2bf(v.y); o.z = f2bf(v.z); o.w = f2bf(v.w);
    ((ushort4*)W1b)[i] = o;
  } else if (g < 18176) {
    int idx = (g - 17920) * 256 + tid;        // 65536: n*64 + q
    int n = idx >> 6, q = idx & 63;
    int e = q >> 3, r = q & 7;
    Btb[(size_t)n * 1088 + 1024 + q] = f2bf(loraB[((size_t)(e * 1024 + n)) * 8 + r]);
  } else {
    int i = (g - 18176) * 256 + tid;          // 16384 float4 groups
    float4 v = ((const float4*)loraA)[i];
    ushort4 o;
    o.x = f2bf(v.x); o.y = f2bf(v.y); o.z = f2bf(v.z); o.w = f2bf(v.w);
    ((ushort4*)A2b)[i] = o;
  }
}

// ---------------- router: logits + softmax, one wave per token ----------------
__global__ __launch_bounds__(256) void gates_kernel(const u16* __restrict__ h,
                                                    const float* __restrict__ W2,
                                                    const float* __restrict__ b2,
                                                    const float* __restrict__ temp,
                                                    float* __restrict__ gates) {
  int wave = threadIdx.x >> 6, lane = threadIdx.x & 63;
  int m = blockIdx.x * 4 + wave;
  bf16x8 hv8 = *(const bf16x8*)(h + (size_t)m * 512 + lane * 8);
  float hv[8];
#pragma unroll
  for (int j = 0; j < 8; ++j) hv[j] = bf2f((u16)hv8[j]);
  float p[8] = {};
#pragma unroll
  for (int e = 0; e < 8; ++e) {
    const float* w2r = W2 + e * 512 + lane * 8;
#pragma unroll
    for (int j = 0; j < 8; ++j) p[e] += hv[j] * w2r[j];
  }
#pragma unroll
  for (int off = 32; off > 0; off >>= 1) {
#pragma unroll
    for (int e = 0; e < 8; ++e) p[e] += __shfl_down(p[e], off);
  }
  if (lane == 0) {
    float t = temp[0];
    float lg[8], mx = -1e30f;
#pragma unroll
    for (int e = 0; e < 8; ++e) { lg[e] = (p[e] + b2[e]) / t; mx = fmaxf(mx, lg[e]); }
    float s = 0.f;
#pragma unroll
    for (int e = 0; e < 8; ++e) { lg[e] = expf(lg[e] - mx); s += lg[e]; }
    float inv = 1.f / s;
#pragma unroll
    for (int e = 0; e < 8; ++e) gates[(size_t)m * 8 + e] = lg[e] * inv;
  }
}

// ---------------- m97-style GEMM for the small w-GEMM (MODE 1) ----------
template <int BM, int BN, int MODE>
__global__ __launch_bounds__(256) void gemm_mfma(const u16* __restrict__ A,
                                                 const u16* __restrict__ Bt,
                                                 const u16* __restrict__ A2,
                                                 void* __restrict__ Cv,
                                                 const float* __restrict__ aux,
                                                 int N, int K, int lda, int ldb) {
  constexpr int FM = BM / 32, FN = BN / 32;
  constexpr int AI = BM / 32, BI = BN / 32;
  __shared__ u16 lds[(BM + BN) * 64];
  u16* As = lds;
  u16* Bs = lds + BM * 64;

  const int tid = threadIdx.x;
  const int w = tid >> 6, lane = tid & 63;
  const int wr = w >> 1, wc = w & 1;
  const int m0 = blockIdx.y * BM, n0 = blockIdx.x * BN;

  const uint8_t* Ab = (const uint8_t*)A;
  const uint8_t* Bb = (const uint8_t*)Bt;
  const size_t lda_b = (size_t)lda * 2, ldb_b = (size_t)ldb * 2;

  f32x4 acc[FM][FN] = {};

  const int nk = K >> 6;
  for (int kt = 0; kt < nk; ++kt) {
#pragma unroll
    for (int i = 0; i < AI; ++i) {
      const int lbase = (w * AI + i) * 1024;
      const int o = lbase + lane * 16;
      const int r = o >> 7, cb = o & 127;
      const uint8_t* g = Ab + (size_t)(m0 + r) * lda_b + (size_t)kt * 128 + cb;
      __builtin_amdgcn_global_load_lds((glb_u32_t*)g,
                                       (lds_u32_t*)((uint8_t*)As + lbase), 16, 0, 0);
    }
#pragma unroll
    for (int i = 0; i < BI; ++i) {
      const int lbase = (w * BI + i) * 1024;
      const int o = lbase + lane * 16;
      const int r = o >> 7, cb = o & 127;
      const uint8_t* g = Bb + (size_t)(n0 + r) * ldb_b + (size_t)kt * 128 + cb;
      __builtin_amdgcn_global_load_lds((glb_u32_t*)g,
                                       (lds_u32_t*)((uint8_t*)Bs + lbase), 16, 0, 0);
    }
    __syncthreads();

    bf16x8 af[2][FM], bfv[2][FN];
#pragma unroll
    for (int ks = 0; ks < 2; ++ks) {
      const int col = ks * 32 + ((lane >> 4) << 3);
#pragma unroll
      for (int im = 0; im < FM; ++im) {
        const int row = wr * (BM / 2) + im * 16 + (lane & 15);
        af[ks][im] = *(const bf16x8*)(As + row * 64 + col);
      }
#pragma unroll
      for (int in_ = 0; in_ < FN; ++in_) {
        const int row = wc * (BN / 2) + in_ * 16 + (lane & 15);
        bfv[ks][in_] = *(const bf16x8*)(Bs + row * 64 + col);
      }
    }
#pragma unroll
    for (int ks = 0; ks < 2; ++ks)
#pragma unroll
      for (int im = 0; im < FM; ++im)
#pragma unroll
        for (int in_ = 0; in_ < FN; ++in_)
          acc[im][in_] = __builtin_amdgcn_mfma_f32_16x16x32_bf16(
              af[ks][im], bfv[ks][in_], acc[im][in_], 0, 0, 0);
    __syncthreads();
  }

#pragma unroll
  for (int im = 0; im < FM; ++im)
#pragma unroll
    for (int in_ = 0; in_ < FN; ++in_) {
      const int col = n0 + wc * (BN / 2) + in_ * 16 + (lane & 15);
#pragma unroll
      for (int j = 0; j < 4; ++j) {
        const int row = m0 + wr * (BM / 2) + im * 16 + ((lane >> 4) << 2) + j;
        float v = acc[im][in_][j];
        if constexpr (MODE == 1) {
          v *= aux[(size_t)row * 8 + (col >> 3)];
          ((u16*)Cv)[(size_t)row * N + col] = f2bf(v);
        } else {
          ((float*)Cv)[(size_t)row * N + col] = v;
        }
      }
    }
}

// ============ round-4 proven 8-phase GEMM: half-tile stages, counted vmcnt ============
// C[m][n] = sum_k A[m][k]*Bt[n][k]. 512 thr = 8 waves (2M x 4N), per-wave BM/2 x BN/4.
// Phase: [ds_reads for THIS phase's MFMA][stage 1 half-tile][BAR][SP1; 16 MFMA; SP0][BAR]
// vmcnt counted at phases 4/8 only. T2 XOR-swizzle (pre-swizzled global src).
// MODE 0: bf16 relu(acc+aux[n]).  MODE 2: last K-tile's A from A2 (128B rows), f32 store.
#define MFMA_Q(mh, nh)                                                         \
  _Pragma("unroll") for (int im2 = 0; im2 < FMH; ++im2)                        \
  _Pragma("unroll") for (int in2 = 0; in2 < FNH; ++in2)                        \
  _Pragma("unroll") for (int ks = 0; ks < 2; ++ks)                             \
      acc[(mh) * FMH + im2][(nh) * FNH + in2] =                                \
          __builtin_amdgcn_mfma_f32_16x16x32_bf16(                             \
              af[im2][ks], bfr[nh][in2][ks],                                   \
              acc[(mh) * FMH + im2][(nh) * FNH + in2], 0, 0, 0);

#define VMCNT(n) asm volatile("s_waitcnt vmcnt(%0)" ::"i"(n) : "memory")
#define BAR asm volatile("s_barrier" ::: "memory")
#define SP(x) __builtin_amdgcn_s_setprio(x)

template <int BM, int BN, int MODE>
__global__ __launch_bounds__(512, 2) void gemm8p(const u16* __restrict__ A,
                                                 const u16* __restrict__ Bt,
                                                 const u16* __restrict__ A2,
                                                 void* __restrict__ Cv,
                                                 const float* __restrict__ aux,
                                                 const int N, const int K,
                                                 const int lda, const int ldb) {
  constexpr int FM = BM / 32;                   // m-frags per wave (BM/2 rows)
  constexpr int FNW = BN / 64;                  // n-frags per wave (BN/4 cols)
  constexpr int FMH = FM / 2;
  constexpr int FNH = (FNW >= 2) ? FNW / 2 : 1;
  constexpr int NBH = BN / 128;                 // B half-tiles per K-tile (2 or 1)
  constexpr int VMC = 2 * NBH;                  // counted vmcnt
  constexpr int BUFB = (BM + BN) * 128;         // bytes per K-tile buffer

  __shared__ __align__(16) uint8_t lds[2 * BUFB];

  const int tid = threadIdx.x;
  const int lane = tid & 63, w = tid >> 6;
  const int wr = w >> 2, wcn = w & 3;
  const int l15 = lane & 15, lhi = lane >> 4;
  const int xorv = (lane & 7) << 4;
  const int c0 = (lhi * 16) ^ xorv;        // ks=0 col-byte (swizzled)
  const int c1 = (64 + lhi * 16) ^ xorv;   // ks=1

  // T1: bijective XCD swizzle; grid is exactly 256 blocks (32 per XCD).
  const int f = blockIdx.x;
  const int idx = (f & 7) * 32 + (f >> 3);
  const int gx = N / BN;
  const int m0 = (idx / gx) * BM;
  const int n0 = (idx % gx) * BN;

  const size_t lda_b = (size_t)lda * 2, ldb_b = (size_t)ldb * 2;
  const int nk = K >> 6;

  const int arow0 = (wr * (BM / 2) + l15) * 128;
  const int brow0 = (wcn * (BN / 4) + l15) * 128;

  f32x4 acc[FM][FNW] = {};
  bf16x8 af[FMH][2];
  bf16x8 bfr[2][FNH][2];

  // ---- stage one 16KB half-tile (2 global_load_lds per wave) ----
  auto stageA = [&](int h, int kt, int b) {
    const int ktc = kt < nk ? kt : nk - 1;
    const bool last = (MODE == 2) && (ktc == nk - 1);
    uint8_t* dst = lds + b * BUFB + h * (BM * 64) + w * 1024;
#pragma unroll
    for (int i = 0; i < 2; ++i) {
      const int off = i * 8192 + tid * 16;
      const int row = h * (BM / 2) + (off >> 7);
      const int ss = ((off >> 4) & 7) ^ (row & 7);  // inverse-swizzled source
      const uint8_t* g =
          last ? (const uint8_t*)A2 + (size_t)(m0 + row) * 128 + ss * 16
               : (const uint8_t*)A + (size_t)(m0 + row) * lda_b + ktc * 128 + ss * 16;
      __builtin_amdgcn_global_load_lds((glb_u32_t*)g, (lds_u32_t*)(dst + i * 8192),
                                       16, 0, 0);
    }
  };
  auto stageB = [&](int h, int kt, int b) {
    const int ktc = kt < nk ? kt : nk - 1;
    uint8_t* dst = lds + b * BUFB + BM * 128 + h * (BN * 64) + w * 1024;
#pragma unroll
    for (int i = 0; i < 2; ++i) {
      const int off = i * 8192 + tid * 16;
      const int row = h * (BN / 2) + (off >> 7);
      const int ss = ((off >> 4) & 7) ^ (row & 7);
      const uint8_t* g =
          (const uint8_t*)Bt + (size_t)(n0 + row) * ldb_b + ktc * 128 + ss * 16;
      __builtin_amdgcn_global_load_lds((glb_u32_t*)g, (lds_u32_t*)(dst + i * 8192),
                                       16, 0, 0);
    }
  };

  auto loadA = [&](int mh, const uint8_t* buf) {
#pragma unroll
    for (int im2 = 0; im2 < FMH; ++im2) {
      const uint8_t* p = buf + arow0 + mh * (FMH * 2048) + im2 * 2048;
      af[im2][0] = *(const bf16x8*)(p + c0);
      af[im2][1] = *(const bf16x8*)(p + c1);
    }
  };
  auto loadB = [&](int nh, const uint8_t* buf) {
#pragma unroll
    for (int in2 = 0; in2 < FNH; ++in2) {
      const uint8_t* p = buf + BM * 128 + brow0 + nh * (FNH * 2048) + in2 * 2048;
      bfr[nh][in2][0] = *(const bf16x8*)(p + c0);
      bfr[nh][in2][1] = *(const bf16x8*)(p + c1);
    }
  };

  // ---- prologue: tile0 (A+B) -> buf0, tile1 B -> buf1 ----
  stageA(0, 0, 0); stageA(1, 0, 0);
  stageB(0, 0, 0); if constexpr (NBH == 2) stageB(1, 0, 0);
  stageB(0, 1, 1); if constexpr (NBH == 2) stageB(1, 1, 1);
  VMCNT(VMC); BAR;

  const uint8_t* b0 = lds;
  const uint8_t* b1 = lds + BUFB;
  const int NIT = nk >> 1;

  for (int it = 0; it < NIT; ++it) {
    const int u = it * 2;
    // P1: tile u, Q(0,0)
    loadA(0, b0); loadB(0, b0);
    stageA(0, u + 1, 1);
    BAR; SP(1); MFMA_Q(0, 0); SP(0); BAR;
    // P2: Q(0,1)
    loadB(1, b0);
    stageA(1, u + 1, 1);
    BAR; SP(1); MFMA_Q(0, 1); SP(0); BAR;
    // P3: Q(1,1)
    loadA(1, b0);
    stageB(0, u + 2, 0);
    BAR; SP(1); MFMA_Q(1, 1); SP(0); BAR;
    // P4: Q(1,0) + counted wait (completes tile u+1's A; B is older)
    if constexpr (NBH == 2) stageB(1, u + 2, 0);
    VMCNT(VMC);
    BAR; SP(1); MFMA_Q(1, 0); SP(0); BAR;
    // P5: tile u+1, Q(0,0)
    loadA(0, b1); loadB(0, b1);
    stageA(0, u + 2, 0);
    BAR; SP(1); MFMA_Q(0, 0); SP(0); BAR;
    // P6: Q(0,1)
    loadB(1, b1);
    stageA(1, u + 2, 0);
    BAR; SP(1); MFMA_Q(0, 1); SP(0); BAR;
    // P7: Q(1,1)
    loadA(1, b1);
    stageB(0, u + 3, 1);
    BAR; SP(1); MFMA_Q(1, 1); SP(0); BAR;
    // P8: Q(1,0) + counted wait (completes tile u+2)
    if constexpr (NBH == 2) stageB(1, u + 3, 1);
    VMCNT(VMC);
    BAR; SP(1); MFMA_Q(1, 0); SP(0); BAR;
  }

  // ---- tail K-tile (odd nk): buf0 fully staged & waited by last P8 ----
  if (nk & 1) {
    loadA(0, b0); loadB(0, b0);
    SP(1); MFMA_Q(0, 0); SP(0);
    loadB(1, b0);
    SP(1); MFMA_Q(0, 1); SP(0);
    loadA(1, b0);
    SP(1); MFMA_Q(1, 1); MFMA_Q(1, 0); SP(0);
  }

  // ---- epilogue: C/D map col=lane&15, row=(lane>>4)*4+j ----
#pragma unroll
  for (int im = 0; im < FM; ++im) {
#pragma unroll
    for (int in_ = 0; in_ < FNW; ++in_) {
      const int col = n0 + wcn * (BN / 4) + in_ * 16 + l15;
#pragma unroll
      for (int j = 0; j < 4; ++j) {
        const int row = m0 + wr * (BM / 2) + im * 16 + lhi * 4 + j;
        float v = acc[im][in_][j];
        if constexpr (MODE == 0) {
          v = fmaxf(v + aux[col], 0.f);
          ((u16*)Cv)[(size_t)row * N + col] = f2bf(v);
        } else {
          ((float*)Cv)[(size_t)row * N + col] = v;
        }
      }
    }
  }
}

extern "C" void kernel_launch(void* const* d_in, const int* in_sizes, int n_in,
                              void* d_out, int out_size, void* d_ws, size_t ws_size,
                              hipStream_t stream) {
  const float* x     = (const float*)d_in[0];  // [16384][1024]
  const float* Wb    = (const float*)d_in[1];  // [1024][1024]
  const float* rW1   = (const float*)d_in[2];  // [512][1024]
  const float* rb1   = (const float*)d_in[3];  // [512]
  const float* rW2   = (const float*)d_in[4];  // [8][512]
  const float* rb2   = (const float*)d_in[5];  // [8]
  const float* temp  = (const float*)d_in[6];  // [1]
  const float* loraA = (const float*)d_in[7];  // [64][1024]
  const float* loraB = (const float*)d_in[8];  // [8][1024][8]
  float* out = (float*)d_out;

  uint8_t* p = (uint8_t*)d_ws;
  u16* xb   = (u16*)p;                 p += (size_t)M_TOK * 1024 * 2;
  u16* hb   = (u16*)p;                 p += (size_t)M_TOK * 512 * 2;
  u16* wb   = (u16*)p;                 p += (size_t)M_TOK * 64 * 2;
  u16* Btb  = (u16*)p;                 p += (size_t)1024 * 1088 * 2;
  u16* W1b  = (u16*)p;                 p += (size_t)512 * 1024 * 2;
  u16* A2b  = (u16*)p;                 p += (size_t)64 * 1024 * 2;
  float* gates = (float*)p;

  // ---- fused prep: all conversions + gathers in one launch ----
  prep_k<<<18240, 256, 0, stream>>>(x, Wb, rW1, loraA, loraB, xb, Btb, W1b, A2b);

  // ---- h = relu(x @ W1^T + b1) -> bf16 [16384][512] (8-phase) ----
  gemm8p<256, 128, 0><<<256, 512, 0, stream>>>(xb, W1b, nullptr, hb, rb1,
                                               512, 1024, 1024, 1024);

  // ---- gates = softmax((h @ W2^T + b2)/T) ----
  gates_kernel<<<M_TOK / 4, 256, 0, stream>>>(hb, rW2, rb2, temp, gates);

  // ---- w = (x @ A^T) * gate -> bf16 [16384][64] (m97-style, 256 blocks) ----
  gemm_mfma<64, 64, 1><<<dim3(1, M_TOK / 64), 256, 0, stream>>>(
      xb, A2b, nullptr, wb, gates, 64, 1024, 1024, 1024);

  // ---- out = [x | w] @ [Wb^T ; B2] -> f32 [16384][1024], K=1088 (8-phase) ----
  gemm8p<256, 256, 2><<<256, 512, 0, stream>>>(xb, Btb, wb, out, nullptr,
                                               1024, 1088, 1024, 1088);
}